// Round 11
// baseline (171.435 us; speedup 1.0000x reference)
//
#include <hip/hip_runtime.h>

// Problem: B=8, C=512, H*W=1024 spatial, 8 heads x d=64, GROUPS=32.
// Pipeline: prep(GN+weights) -> QKV GEMM (V written pre-transposed) -> attn
// -> out-proj (+res).
// Round 11: transpose_v fused into gemm_qkv. For V output-blocks (col0>=1024)
// the MFMA operand order is swapped -> accumulators hold C^T, epilogue writes
// g_vt[bh][d][s] directly (same coalescing; lane sweeps s). Kills one
// dispatch + 32 MB of traffic. attn/prep/gemm_out unchanged from r10.

typedef __attribute__((ext_vector_type(8))) short bf16x8;   // 8 bf16 in 4 VGPRs
typedef __attribute__((ext_vector_type(4))) short bf16x4;   // 4 bf16 (8B)
typedef __attribute__((ext_vector_type(4))) float f32x4;

#define NB 8
#define NC 512
#define HW 1024
#define NHEAD 8
#define DHEAD 64
#define GROUPS 32
#define CPG 16          // channels per group
#define QKV_N 1536

// global -> LDS direct copy, 16B per lane; lds base must be wave-uniform.
#define GLL16(gaddr, ldsaddr)                                                  \
    __builtin_amdgcn_global_load_lds(                                          \
        (const __attribute__((address_space(1))) unsigned*)(gaddr),            \
        (__attribute__((address_space(3))) unsigned*)(ldsaddr), 16, 0, 0)

// Scratch in device globals.
__device__ alignas(64) short g_xn[(size_t)8192 * 512];      // GN out, pixel-major [bs][c]
__device__ alignas(64) short g_qkv[(size_t)8192 * 1536];    // Q,K parts [bs][c] (V unused)
__device__ alignas(64) short g_vt[(size_t)64 * 64 * 1024];  // V^T [b*8+h][d][s]
__device__ alignas(64) short g_attno[(size_t)8192 * 512];   // attention out [bs][c]
__device__ alignas(64) short g_wqkv[(size_t)1536 * 512];    // w_qkv as bf16 [o][c]
__device__ alignas(64) short g_wout[(size_t)512 * 512];     // w_out as bf16 [o][c]

__device__ __forceinline__ float b2f(short h) {
    union { unsigned u; float f; } v;
    v.u = ((unsigned)(unsigned short)h) << 16;
    return v.f;
}
__device__ __forceinline__ short f2b(float f) {
    union { float f; unsigned u; } v;
    v.f = f;
    unsigned r = v.u + 0x7fff + ((v.u >> 16) & 1);   // RNE
    return (short)(r >> 16);
}

// ---------------------------------------------------------------------------
// Kernel 1: prep = GroupNorm (blocks 0..255) + weight conversion (256..319).
// ---------------------------------------------------------------------------
__global__ __launch_bounds__(256) void prep_kernel(
    const float* __restrict__ x, const float* __restrict__ gamma,
    const float* __restrict__ beta, const float* __restrict__ wqkv,
    const float* __restrict__ wout) {
    int tid = threadIdx.x;
    if (blockIdx.x >= 256) {                 // ---- weight conversion part
        int wb = blockIdx.x - 256;           // 0..63
        for (int i = wb * 256 + tid; i < 1536 * 512; i += 64 * 256) {
            float v = wqkv[i];
            if (i < 512 * 512) v *= 0.125f;  // Q rows: fold 1/sqrt(d)
            g_wqkv[i] = f2b(v);
        }
        for (int i = wb * 256 + tid; i < 512 * 512; i += 64 * 256)
            g_wout[i] = f2b(wout[i]);
        return;
    }
    // ---- GroupNorm part
    int b = blockIdx.x >> 5, g = blockIdx.x & 31;
    __shared__ alignas(16) short tile[CPG][HW];          // 32 KB
    __shared__ float red[2][4];
    __shared__ float sg[CPG], sb[CPG];
    if (tid < CPG) {
        int cg = g * CPG + tid;
        sg[tid] = gamma[cg];
        sb[tid] = beta[cg];
    }
    const float* xb = x + (size_t)b * NC * HW + (size_t)g * CPG * HW;
    float s1 = 0.f, s2 = 0.f;
    #pragma unroll
    for (int it = 0; it < 8; it++) {
        int idx = tid + it * 256;
        f32x4 v0 = *(const f32x4*)(xb + idx * 8);
        f32x4 v1 = *(const f32x4*)(xb + idx * 8 + 4);
        bf16x8 w;
        #pragma unroll
        for (int j = 0; j < 4; j++) {
            s1 += v0[j] + v1[j]; s2 += v0[j] * v0[j] + v1[j] * v1[j];
            w[j] = f2b(v0[j]); w[j + 4] = f2b(v1[j]);
        }
        *(bf16x8*)(&((short*)tile)[idx * 8]) = w;
    }
    #pragma unroll
    for (int off = 32; off; off >>= 1) { s1 += __shfl_xor(s1, off); s2 += __shfl_xor(s2, off); }
    int wid = tid >> 6;
    if ((tid & 63) == 0) { red[0][wid] = s1; red[1][wid] = s2; }
    __syncthreads();
    float t1 = red[0][0] + red[0][1] + red[0][2] + red[0][3];
    float t2 = red[1][0] + red[1][1] + red[1][2] + red[1][3];
    float mean = t1 * (1.f / 16384.f);
    float var  = t2 * (1.f / 16384.f) - mean * mean;
    float inv  = rsqrtf(var + 1e-5f);
    #pragma unroll
    for (int p = 0; p < 4; p++) {
        int s = tid * 4 + p;
        bf16x8 pk0, pk1;
        #pragma unroll
        for (int cc = 0; cc < 8; cc++) {
            pk0[cc] = f2b((b2f(tile[cc][s])     - mean) * inv * sg[cc]     + sb[cc]);
            pk1[cc] = f2b((b2f(tile[cc + 8][s]) - mean) * inv * sg[cc + 8] + sb[cc + 8]);
        }
        size_t dst = ((size_t)(b * HW + s)) * NC + g * CPG;
        *(bf16x8*)(g_xn + dst)     = pk0;
        *(bf16x8*)(g_xn + dst + 8) = pk1;
    }
}

// ---------------------------------------------------------------------------
// Kernel 2: QKV GEMM, m97 structure + fused V-transpose epilogue.
// M=8192 N=1536 K=512. For col0>=1024 (V blocks) the MFMA operands are
// swapped: acc holds C^T (rows=o, cols=bs) -> write g_vt[bh][d][s] directly.
// ---------------------------------------------------------------------------
__global__ __launch_bounds__(256) void gemm_qkv() {
    const int K = NC;
    int tid = threadIdx.x, lane = tid & 63, wid = tid >> 6;
    int quad = lane >> 4, l15 = lane & 15;
    int row0 = blockIdx.x * 128;
    int col0 = blockIdx.y * 128;
    bool vblk = (col0 >= 1024);
    __shared__ alignas(16) short sa[128 * 32];   // 8 KB
    __shared__ alignas(16) short sbuf[128 * 32]; // 8 KB
    int srow = wid * 32 + (lane >> 2);
    int scol = (lane & 3) * 8;
    const short* ga = g_xn   + (size_t)(row0 + srow) * K + scol;
    const short* gb = g_wqkv + (size_t)(col0 + srow) * K + scol;
    short* la = sa   + wid * 1024;
    short* lb = sbuf + wid * 1024;
    int mw = (wid >> 1) * 64, nw = (wid & 1) * 64;
    f32x4 acc[4][4] = {};
    for (int k = 0; k < K; k += 32) {
        GLL16(ga + k, la);
        GLL16(ga + (size_t)16 * K + k, la + 512);
        GLL16(gb + k, lb);
        GLL16(gb + (size_t)16 * K + k, lb + 512);
        __syncthreads();
        bf16x8 af[4], bfv[4];
        #pragma unroll
        for (int m = 0; m < 4; m++) af[m]  = *(const bf16x8*)&sa[(mw + m * 16 + l15) * 32 + quad * 8];
        #pragma unroll
        for (int n = 0; n < 4; n++) bfv[n] = *(const bf16x8*)&sbuf[(nw + n * 16 + l15) * 32 + quad * 8];
        if (vblk) {
            #pragma unroll
            for (int m = 0; m < 4; m++)
                #pragma unroll
                for (int n = 0; n < 4; n++)
                    acc[m][n] = __builtin_amdgcn_mfma_f32_16x16x32_bf16(bfv[n], af[m], acc[m][n], 0, 0, 0);
        } else {
            #pragma unroll
            for (int m = 0; m < 4; m++)
                #pragma unroll
                for (int n = 0; n < 4; n++)
                    acc[m][n] = __builtin_amdgcn_mfma_f32_16x16x32_bf16(af[m], bfv[n], acc[m][n], 0, 0, 0);
        }
        __syncthreads();
    }
    if (vblk) {
        // acc[m][n] = C^T tile: row = o (V channel), col = bs.
        #pragma unroll
        for (int m = 0; m < 4; m++)
            #pragma unroll
            for (int n = 0; n < 4; n++)
                #pragma unroll
                for (int r = 0; r < 4; r++) {
                    int o  = col0 - 1024 + nw + n * 16 + quad * 4 + r;  // 0..511
                    int bs = row0 + mw + m * 16 + l15;
                    int bh = (bs >> 10) * 8 + (o >> 6);
                    g_vt[((size_t)(bh * 64 + (o & 63))) * HW + (bs & 1023)] = f2b(acc[m][n][r]);
                }
    } else {
        #pragma unroll
        for (int m = 0; m < 4; m++)
            #pragma unroll
            for (int n = 0; n < 4; n++)
                #pragma unroll
                for (int r = 0; r < 4; r++) {
                    int row = row0 + mw + m * 16 + quad * 4 + r;
                    int col = col0 + nw + n * 16 + l15;
                    g_qkv[(size_t)row * QKV_N + col] = f2b(acc[m][n][r]);
                }
    }
}

// ---------------------------------------------------------------------------
// Kernel 3: flash attention (unchanged from r10).
// Grid 1024: bh = blk&63 (XCD L2 sharing), qt = blk>>6. 4 waves x 16 q-rows.
// ---------------------------------------------------------------------------
__global__ __launch_bounds__(256) void attn_kernel() {
    int bh = blockIdx.x & 63, qt = blockIdx.x >> 6;
    int b = bh >> 3, h = bh & 7;
    int tid = threadIdx.x, lane = tid & 63, wid = tid >> 6;
    int quad = lane >> 4, l15 = lane & 15;
    __shared__ alignas(16) short kt[2][64 * 64];    // 8 KB each, swizzled
    __shared__ alignas(16) short vt[2][64 * 64];    // 8 KB each, swizzled
    __shared__ alignas(16) short pt4[4][16][16][4]; // per-wave P, 2 KB each
    int qrow0 = qt * 64 + wid * 16;

    const short* qb = g_qkv + ((size_t)(b * HW + qrow0 + l15)) * QKV_N + h * DHEAD + quad * 8;
    bf16x8 aq0 = *(const bf16x8*)qb;
    bf16x8 aq1 = *(const bf16x8*)(qb + 32);
    f32x4 acc_o[4] = {};
    float l_part = 0.f;                              // lane m=l15 partial

    int r_lo = lane >> 3;
    int s_log = (lane & 7) ^ r_lo;
    int swz = l15 & 7;                               // fragment-read swizzle

    auto stage = [&](int it, int bufi) {
        int t0 = it * 64;
        #pragma unroll
        for (int c = 0; c < 2; c++) {
            int r = wid * 16 + c * 8 + r_lo;
            GLL16(g_qkv + ((size_t)(b * HW + t0 + r)) * QKV_N + 512 + h * DHEAD + s_log * 8,
                  &kt[bufi][(wid * 16 + c * 8) * 64]);
            GLL16(g_vt + ((size_t)(bh * 64 + r)) * HW + t0 + s_log * 8,
                  &vt[bufi][(wid * 16 + c * 8) * 64]);
        }
    };

    stage(0, 0);
    __syncthreads();
    for (int it = 0; it < 16; it++) {
        int cur = it & 1;
        if (it < 15) stage(it + 1, cur ^ 1);        // prefetch into alt buffer
        #pragma unroll
        for (int sub = 0; sub < 4; sub++) {
            int row = sub * 16 + l15;
            bf16x8 k0 = *(const bf16x8*)&kt[cur][row * 64 + ((quad ^ swz) * 8)];
            bf16x8 k1 = *(const bf16x8*)&kt[cur][row * 64 + (((4 + quad) ^ swz) * 8)];
            f32x4 z = {};
            z = __builtin_amdgcn_mfma_f32_16x16x32_bf16(k0, aq0, z, 0, 0, 0);
            z = __builtin_amdgcn_mfma_f32_16x16x32_bf16(k1, aq1, z, 0, 0, 0);
            unsigned u[4];
            #pragma unroll
            for (int r = 0; r < 4; r++) {
                float e = __expf(z[r]);
                l_part += e;
                union { float f; unsigned b; } cv; cv.f = e;
                u[r] = cv.b + 0x8000u;               // round-half-up to bf16
            }
            union { unsigned w[2]; bf16x4 s; } pk;
            pk.w[0] = (u[0] >> 16) | (u[1] & 0xffff0000u);
            pk.w[1] = (u[2] >> 16) | (u[3] & 0xffff0000u);
            *(bf16x4*)&pt4[wid][sub * 4 + quad][l15][0] = pk.s;
        }
        asm volatile("" ::: "memory");               // order pt4 writes vs reads
        bf16x8 ap0, ap1;
        {
            union { bf16x4 hh[2]; bf16x8 v; } cc;
            cc.hh[0] = *(const bf16x4*)&pt4[wid][quad * 2][l15][0];
            cc.hh[1] = *(const bf16x4*)&pt4[wid][quad * 2 + 1][l15][0];
            ap0 = cc.v;
            cc.hh[0] = *(const bf16x4*)&pt4[wid][8 + quad * 2][l15][0];
            cc.hh[1] = *(const bf16x4*)&pt4[wid][8 + quad * 2 + 1][l15][0];
            ap1 = cc.v;
        }
        #pragma unroll
        for (int nd = 0; nd < 4; nd++) {
            int row = nd * 16 + l15;
            bf16x8 bv0 = *(const bf16x8*)&vt[cur][row * 64 + ((quad ^ swz) * 8)];
            bf16x8 bv1 = *(const bf16x8*)&vt[cur][row * 64 + (((4 + quad) ^ swz) * 8)];
            acc_o[nd] = __builtin_amdgcn_mfma_f32_16x16x32_bf16(ap0, bv0, acc_o[nd], 0, 0, 0);
            acc_o[nd] = __builtin_amdgcn_mfma_f32_16x16x32_bf16(ap1, bv1, acc_o[nd], 0, 0, 0);
        }
        __syncthreads();   // drains prefetch GLLs + all tile reads
    }
    float lf = l_part;
    lf += __shfl_xor(lf, 16); lf += __shfl_xor(lf, 32);
    #pragma unroll
    for (int r = 0; r < 4; r++) {
        float lr = __shfl(lf, quad * 4 + r);         // l for m = quad*4+r
        float invl = 1.f / lr;
        size_t row = (size_t)(b * HW + qrow0 + quad * 4 + r);
        #pragma unroll
        for (int nd = 0; nd < 4; nd++)
            g_attno[row * NC + h * DHEAD + nd * 16 + l15] = f2b(acc_o[nd][r] * invl);
    }
}

// ---------------------------------------------------------------------------
// Kernel 4: out-proj GEMM + residual, m97 structure (unchanged).
// ---------------------------------------------------------------------------
__global__ __launch_bounds__(256) void gemm_out(
    const float* __restrict__ xres, float* __restrict__ out) {
    const int K = NC;
    int tid = threadIdx.x, lane = tid & 63, wid = tid >> 6;
    int quad = lane >> 4, l15 = lane & 15;
    int row0 = blockIdx.x * 128;   // o
    int col0 = blockIdx.y * 128;   // bs
    __shared__ alignas(16) short sa[128 * 32];
    __shared__ alignas(16) short sbuf[128 * 32];
    int srow = wid * 32 + (lane >> 2);
    int scol = (lane & 3) * 8;
    const short* ga = g_wout  + (size_t)(row0 + srow) * K + scol;
    const short* gb = g_attno + (size_t)(col0 + srow) * K + scol;
    short* la = sa   + wid * 1024;
    short* lb = sbuf + wid * 1024;
    int mw = (wid >> 1) * 64, nw = (wid & 1) * 64;
    f32x4 acc[4][4] = {};
    for (int k = 0; k < K; k += 32) {
        GLL16(ga + k, la);
        GLL16(ga + (size_t)16 * K + k, la + 512);
        GLL16(gb + k, lb);
        GLL16(gb + (size_t)16 * K + k, lb + 512);
        __syncthreads();
        bf16x8 af[4], bfv[4];
        #pragma unroll
        for (int m = 0; m < 4; m++) af[m]  = *(const bf16x8*)&sa[(mw + m * 16 + l15) * 32 + quad * 8];
        #pragma unroll
        for (int n = 0; n < 4; n++) bfv[n] = *(const bf16x8*)&sbuf[(nw + n * 16 + l15) * 32 + quad * 8];
        #pragma unroll
        for (int m = 0; m < 4; m++)
            #pragma unroll
            for (int n = 0; n < 4; n++)
                acc[m][n] = __builtin_amdgcn_mfma_f32_16x16x32_bf16(af[m], bfv[n], acc[m][n], 0, 0, 0);
        __syncthreads();
    }
    #pragma unroll
    for (int m = 0; m < 4; m++)
        #pragma unroll
        for (int n = 0; n < 4; n++)
            #pragma unroll
            for (int r = 0; r < 4; r++) {
                int o  = row0 + mw + m * 16 + quad * 4 + r;
                int bs = col0 + nw + n * 16 + l15;
                size_t addr = (size_t)(bs >> 10) * ((size_t)NC * HW) + (size_t)o * HW + (bs & 1023);
                out[addr] = acc[m][n][r] + xres[addr];
            }
}

// ---------------------------------------------------------------------------
extern "C" void kernel_launch(void* const* d_in, const int* in_sizes, int n_in,
                              void* d_out, int out_size, void* d_ws, size_t ws_size,
                              hipStream_t stream) {
    const float* x     = (const float*)d_in[0];
    const float* gamma = (const float*)d_in[1];
    const float* beta  = (const float*)d_in[2];
    const float* wqkv  = (const float*)d_in[3];
    const float* wout  = (const float*)d_in[4];
    float* out = (float*)d_out;

    prep_kernel<<<dim3(320), dim3(256), 0, stream>>>(x, gamma, beta, wqkv, wout);
    gemm_qkv<<<dim3(64, 12), dim3(256), 0, stream>>>();
    attn_kernel<<<dim3(1024), dim3(256), 0, stream>>>();
    gemm_out<<<dim3(4, 64), dim3(256), 0, stream>>>(x, out);
}

// Round 12
// 156.227 us; speedup vs baseline: 1.0973x; 1.0973x over previous
//
#include <hip/hip_runtime.h>

// Problem: B=8, C=512, H*W=1024 spatial, 8 heads x d=64, GROUPS=32.
// Pipeline: prep(GN+weights) -> QKV GEMM -> V-transpose -> attn -> out-proj.
// Round 12: REVERT to r10 (best: 156.4us). r11's fused V-transpose epilogue
// regressed +15us (2-byte scattered stores from the register-fat GEMM vs the
// standalone transpose kernel's coalesced 16B/lane at 8 VGPRs). r10 config:
// attn grid 1024 (16 q-rows/wave, 40KB LDS, 4 blocks/CU), S^T=K*Q^T trick,
// b64-packed P, swizzled GLL staging, XCD-aware bh swizzle, m97 GEMMs.

typedef __attribute__((ext_vector_type(8))) short bf16x8;   // 8 bf16 in 4 VGPRs
typedef __attribute__((ext_vector_type(4))) short bf16x4;   // 4 bf16 (8B)
typedef __attribute__((ext_vector_type(4))) float f32x4;

#define NB 8
#define NC 512
#define HW 1024
#define NHEAD 8
#define DHEAD 64
#define GROUPS 32
#define CPG 16          // channels per group
#define QKV_N 1536

// global -> LDS direct copy, 16B per lane; lds base must be wave-uniform.
#define GLL16(gaddr, ldsaddr)                                                  \
    __builtin_amdgcn_global_load_lds(                                          \
        (const __attribute__((address_space(1))) unsigned*)(gaddr),            \
        (__attribute__((address_space(3))) unsigned*)(ldsaddr), 16, 0, 0)

// Scratch in device globals.
__device__ alignas(64) short g_xn[(size_t)8192 * 512];      // GN out, pixel-major [bs][c]
__device__ alignas(64) short g_qkv[(size_t)8192 * 1536];    // QKV GEMM out [bs][3C]
__device__ alignas(64) short g_vt[(size_t)64 * 64 * 1024];  // V^T [b*8+h][d][s]
__device__ alignas(64) short g_attno[(size_t)8192 * 512];   // attention out [bs][c]
__device__ alignas(64) short g_wqkv[(size_t)1536 * 512];    // w_qkv as bf16 [o][c]
__device__ alignas(64) short g_wout[(size_t)512 * 512];     // w_out as bf16 [o][c]

__device__ __forceinline__ float b2f(short h) {
    union { unsigned u; float f; } v;
    v.u = ((unsigned)(unsigned short)h) << 16;
    return v.f;
}
__device__ __forceinline__ short f2b(float f) {
    union { float f; unsigned u; } v;
    v.f = f;
    unsigned r = v.u + 0x7fff + ((v.u >> 16) & 1);   // RNE
    return (short)(r >> 16);
}

// ---------------------------------------------------------------------------
// Kernel 1: prep = GroupNorm (blocks 0..255) + weight conversion (256..319).
// ---------------------------------------------------------------------------
__global__ __launch_bounds__(256) void prep_kernel(
    const float* __restrict__ x, const float* __restrict__ gamma,
    const float* __restrict__ beta, const float* __restrict__ wqkv,
    const float* __restrict__ wout) {
    int tid = threadIdx.x;
    if (blockIdx.x >= 256) {                 // ---- weight conversion part
        int wb = blockIdx.x - 256;           // 0..63
        for (int i = wb * 256 + tid; i < 1536 * 512; i += 64 * 256) {
            float v = wqkv[i];
            if (i < 512 * 512) v *= 0.125f;  // Q rows: fold 1/sqrt(d)
            g_wqkv[i] = f2b(v);
        }
        for (int i = wb * 256 + tid; i < 512 * 512; i += 64 * 256)
            g_wout[i] = f2b(wout[i]);
        return;
    }
    // ---- GroupNorm part
    int b = blockIdx.x >> 5, g = blockIdx.x & 31;
    __shared__ alignas(16) short tile[CPG][HW];          // 32 KB
    __shared__ float red[2][4];
    __shared__ float sg[CPG], sb[CPG];
    if (tid < CPG) {
        int cg = g * CPG + tid;
        sg[tid] = gamma[cg];
        sb[tid] = beta[cg];
    }
    const float* xb = x + (size_t)b * NC * HW + (size_t)g * CPG * HW;
    float s1 = 0.f, s2 = 0.f;
    #pragma unroll
    for (int it = 0; it < 8; it++) {
        int idx = tid + it * 256;
        f32x4 v0 = *(const f32x4*)(xb + idx * 8);
        f32x4 v1 = *(const f32x4*)(xb + idx * 8 + 4);
        bf16x8 w;
        #pragma unroll
        for (int j = 0; j < 4; j++) {
            s1 += v0[j] + v1[j]; s2 += v0[j] * v0[j] + v1[j] * v1[j];
            w[j] = f2b(v0[j]); w[j + 4] = f2b(v1[j]);
        }
        *(bf16x8*)(&((short*)tile)[idx * 8]) = w;
    }
    #pragma unroll
    for (int off = 32; off; off >>= 1) { s1 += __shfl_xor(s1, off); s2 += __shfl_xor(s2, off); }
    int wid = tid >> 6;
    if ((tid & 63) == 0) { red[0][wid] = s1; red[1][wid] = s2; }
    __syncthreads();
    float t1 = red[0][0] + red[0][1] + red[0][2] + red[0][3];
    float t2 = red[1][0] + red[1][1] + red[1][2] + red[1][3];
    float mean = t1 * (1.f / 16384.f);
    float var  = t2 * (1.f / 16384.f) - mean * mean;
    float inv  = rsqrtf(var + 1e-5f);
    #pragma unroll
    for (int p = 0; p < 4; p++) {
        int s = tid * 4 + p;
        bf16x8 pk0, pk1;
        #pragma unroll
        for (int cc = 0; cc < 8; cc++) {
            pk0[cc] = f2b((b2f(tile[cc][s])     - mean) * inv * sg[cc]     + sb[cc]);
            pk1[cc] = f2b((b2f(tile[cc + 8][s]) - mean) * inv * sg[cc + 8] + sb[cc + 8]);
        }
        size_t dst = ((size_t)(b * HW + s)) * NC + g * CPG;
        *(bf16x8*)(g_xn + dst)     = pk0;
        *(bf16x8*)(g_xn + dst + 8) = pk1;
    }
}

// ---------------------------------------------------------------------------
// Kernel 2: QKV GEMM, m97 structure. M=8192 N=1536 K=512.
// ---------------------------------------------------------------------------
__global__ __launch_bounds__(256) void gemm_qkv() {
    const int K = NC;
    int tid = threadIdx.x, lane = tid & 63, wid = tid >> 6;
    int quad = lane >> 4, l15 = lane & 15;
    int row0 = blockIdx.x * 128;
    int col0 = blockIdx.y * 128;
    __shared__ alignas(16) short sa[128 * 32];   // 8 KB
    __shared__ alignas(16) short sbuf[128 * 32]; // 8 KB
    int srow = wid * 32 + (lane >> 2);
    int scol = (lane & 3) * 8;
    const short* ga = g_xn   + (size_t)(row0 + srow) * K + scol;
    const short* gb = g_wqkv + (size_t)(col0 + srow) * K + scol;
    short* la = sa   + wid * 1024;
    short* lb = sbuf + wid * 1024;
    int mw = (wid >> 1) * 64, nw = (wid & 1) * 64;
    f32x4 acc[4][4] = {};
    for (int k = 0; k < K; k += 32) {
        GLL16(ga + k, la);
        GLL16(ga + (size_t)16 * K + k, la + 512);
        GLL16(gb + k, lb);
        GLL16(gb + (size_t)16 * K + k, lb + 512);
        __syncthreads();
        bf16x8 af[4], bfv[4];
        #pragma unroll
        for (int m = 0; m < 4; m++) af[m]  = *(const bf16x8*)&sa[(mw + m * 16 + l15) * 32 + quad * 8];
        #pragma unroll
        for (int n = 0; n < 4; n++) bfv[n] = *(const bf16x8*)&sbuf[(nw + n * 16 + l15) * 32 + quad * 8];
        #pragma unroll
        for (int m = 0; m < 4; m++)
            #pragma unroll
            for (int n = 0; n < 4; n++)
                acc[m][n] = __builtin_amdgcn_mfma_f32_16x16x32_bf16(af[m], bfv[n], acc[m][n], 0, 0, 0);
        __syncthreads();
    }
    #pragma unroll
    for (int m = 0; m < 4; m++)
        #pragma unroll
        for (int n = 0; n < 4; n++)
            #pragma unroll
            for (int r = 0; r < 4; r++) {
                int row = row0 + mw + m * 16 + quad * 4 + r;
                int col = col0 + nw + n * 16 + l15;
                g_qkv[(size_t)row * QKV_N + col] = f2b(acc[m][n][r]);
            }
}

// ---------------------------------------------------------------------------
// Kernel 2b: V transpose. g_qkv V-part [bs][c] -> g_vt[bh][d][s].
// ---------------------------------------------------------------------------
__global__ __launch_bounds__(256) void transpose_v() {
    int bh = blockIdx.x & 63, st = blockIdx.x >> 6;     // grid 1024
    int b = bh >> 3, h = bh & 7;
    int tid = threadIdx.x;
    __shared__ alignas(16) short tile[64][72];
    int s0 = st * 64;
    #pragma unroll
    for (int cc = 0; cc < 2; cc++) {
        int idx = tid + cc * 256;
        int s = idx >> 3, dc = idx & 7;
        *(bf16x8*)&tile[s][dc * 8] =
            *(const bf16x8*)(g_qkv + ((size_t)(b * HW + s0 + s)) * QKV_N + 1024 + h * DHEAD + dc * 8);
    }
    __syncthreads();
    #pragma unroll
    for (int cc = 0; cc < 2; cc++) {
        int idx = tid + cc * 256;
        int d = idx & 63, sc = idx >> 6;                // sc wave-uniform
        bf16x8 o;
        #pragma unroll
        for (int j = 0; j < 8; j++) o[j] = tile[sc * 8 + j][d];
        *(bf16x8*)(g_vt + ((size_t)(bh * 64 + d)) * HW + s0 + sc * 8) = o;
    }
}

// ---------------------------------------------------------------------------
// Kernel 3: flash attention (r10 structure).
// Grid 1024: bh = blk&63 (XCD L2 sharing), qt = blk>>6. 4 waves x 16 q-rows.
// LDS 40KB -> 4 blocks/CU. S^T = K*Q^T; P via pt4 b64 path; l via shuffles.
// ---------------------------------------------------------------------------
__global__ __launch_bounds__(256) void attn_kernel() {
    int bh = blockIdx.x & 63, qt = blockIdx.x >> 6;
    int b = bh >> 3, h = bh & 7;
    int tid = threadIdx.x, lane = tid & 63, wid = tid >> 6;
    int quad = lane >> 4, l15 = lane & 15;
    __shared__ alignas(16) short kt[2][64 * 64];    // 8 KB each, swizzled
    __shared__ alignas(16) short vt[2][64 * 64];    // 8 KB each, swizzled
    __shared__ alignas(16) short pt4[4][16][16][4]; // per-wave P, 2 KB each
    int qrow0 = qt * 64 + wid * 16;

    const short* qb = g_qkv + ((size_t)(b * HW + qrow0 + l15)) * QKV_N + h * DHEAD + quad * 8;
    bf16x8 aq0 = *(const bf16x8*)qb;
    bf16x8 aq1 = *(const bf16x8*)(qb + 32);
    f32x4 acc_o[4] = {};
    float l_part = 0.f;                              // lane m=l15 partial

    int r_lo = lane >> 3;
    int s_log = (lane & 7) ^ r_lo;
    int swz = l15 & 7;                               // fragment-read swizzle

    auto stage = [&](int it, int bufi) {
        int t0 = it * 64;
        #pragma unroll
        for (int c = 0; c < 2; c++) {
            int r = wid * 16 + c * 8 + r_lo;
            GLL16(g_qkv + ((size_t)(b * HW + t0 + r)) * QKV_N + 512 + h * DHEAD + s_log * 8,
                  &kt[bufi][(wid * 16 + c * 8) * 64]);
            GLL16(g_vt + ((size_t)(bh * 64 + r)) * HW + t0 + s_log * 8,
                  &vt[bufi][(wid * 16 + c * 8) * 64]);
        }
    };

    stage(0, 0);
    __syncthreads();
    for (int it = 0; it < 16; it++) {
        int cur = it & 1;
        if (it < 15) stage(it + 1, cur ^ 1);        // prefetch into alt buffer
        // S^T(64t x 16m) = K Q^T, then P = exp, b64-packed into pt4.
        #pragma unroll
        for (int sub = 0; sub < 4; sub++) {
            int row = sub * 16 + l15;
            bf16x8 k0 = *(const bf16x8*)&kt[cur][row * 64 + ((quad ^ swz) * 8)];
            bf16x8 k1 = *(const bf16x8*)&kt[cur][row * 64 + (((4 + quad) ^ swz) * 8)];
            f32x4 z = {};
            z = __builtin_amdgcn_mfma_f32_16x16x32_bf16(k0, aq0, z, 0, 0, 0);
            z = __builtin_amdgcn_mfma_f32_16x16x32_bf16(k1, aq1, z, 0, 0, 0);
            unsigned u[4];
            #pragma unroll
            for (int r = 0; r < 4; r++) {
                float e = __expf(z[r]);
                l_part += e;
                union { float f; unsigned b; } cv; cv.f = e;
                u[r] = cv.b + 0x8000u;               // round-half-up to bf16
            }
            union { unsigned w[2]; bf16x4 s; } pk;
            pk.w[0] = (u[0] >> 16) | (u[1] & 0xffff0000u);
            pk.w[1] = (u[2] >> 16) | (u[3] & 0xffff0000u);
            *(bf16x4*)&pt4[wid][sub * 4 + quad][l15][0] = pk.s;
        }
        asm volatile("" ::: "memory");               // order pt4 writes vs reads
        // A-frags of P: lane m=l15, t=half*32+quad*8+j -> two b64 per frag.
        bf16x8 ap0, ap1;
        {
            union { bf16x4 hh[2]; bf16x8 v; } cc;
            cc.hh[0] = *(const bf16x4*)&pt4[wid][quad * 2][l15][0];
            cc.hh[1] = *(const bf16x4*)&pt4[wid][quad * 2 + 1][l15][0];
            ap0 = cc.v;
            cc.hh[0] = *(const bf16x4*)&pt4[wid][8 + quad * 2][l15][0];
            cc.hh[1] = *(const bf16x4*)&pt4[wid][8 + quad * 2 + 1][l15][0];
            ap1 = cc.v;
        }
        // O += P V.
        #pragma unroll
        for (int nd = 0; nd < 4; nd++) {
            int row = nd * 16 + l15;
            bf16x8 bv0 = *(const bf16x8*)&vt[cur][row * 64 + ((quad ^ swz) * 8)];
            bf16x8 bv1 = *(const bf16x8*)&vt[cur][row * 64 + (((4 + quad) ^ swz) * 8)];
            acc_o[nd] = __builtin_amdgcn_mfma_f32_16x16x32_bf16(ap0, bv0, acc_o[nd], 0, 0, 0);
            acc_o[nd] = __builtin_amdgcn_mfma_f32_16x16x32_bf16(ap1, bv1, acc_o[nd], 0, 0, 0);
        }
        __syncthreads();   // drains prefetch GLLs + all tile reads
    }
    // Epilogue: combine quad partials of l, redistribute via shuffle, write.
    float lf = l_part;
    lf += __shfl_xor(lf, 16); lf += __shfl_xor(lf, 32);
    #pragma unroll
    for (int r = 0; r < 4; r++) {
        float lr = __shfl(lf, quad * 4 + r);         // l for m = quad*4+r
        float invl = 1.f / lr;
        size_t row = (size_t)(b * HW + qrow0 + quad * 4 + r);
        #pragma unroll
        for (int nd = 0; nd < 4; nd++)
            g_attno[row * NC + h * DHEAD + nd * 16 + l15] = f2b(acc_o[nd][r] * invl);
    }
}

// ---------------------------------------------------------------------------
// Kernel 4: out-proj GEMM + residual, m97 structure.
// ---------------------------------------------------------------------------
__global__ __launch_bounds__(256) void gemm_out(
    const float* __restrict__ xres, float* __restrict__ out) {
    const int K = NC;
    int tid = threadIdx.x, lane = tid & 63, wid = tid >> 6;
    int quad = lane >> 4, l15 = lane & 15;
    int row0 = blockIdx.x * 128;   // o
    int col0 = blockIdx.y * 128;   // bs
    __shared__ alignas(16) short sa[128 * 32];
    __shared__ alignas(16) short sbuf[128 * 32];
    int srow = wid * 32 + (lane >> 2);
    int scol = (lane & 3) * 8;
    const short* ga = g_wout  + (size_t)(row0 + srow) * K + scol;
    const short* gb = g_attno + (size_t)(col0 + srow) * K + scol;
    short* la = sa   + wid * 1024;
    short* lb = sbuf + wid * 1024;
    int mw = (wid >> 1) * 64, nw = (wid & 1) * 64;
    f32x4 acc[4][4] = {};
    for (int k = 0; k < K; k += 32) {
        GLL16(ga + k, la);
        GLL16(ga + (size_t)16 * K + k, la + 512);
        GLL16(gb + k, lb);
        GLL16(gb + (size_t)16 * K + k, lb + 512);
        __syncthreads();
        bf16x8 af[4], bfv[4];
        #pragma unroll
        for (int m = 0; m < 4; m++) af[m]  = *(const bf16x8*)&sa[(mw + m * 16 + l15) * 32 + quad * 8];
        #pragma unroll
        for (int n = 0; n < 4; n++) bfv[n] = *(const bf16x8*)&sbuf[(nw + n * 16 + l15) * 32 + quad * 8];
        #pragma unroll
        for (int m = 0; m < 4; m++)
            #pragma unroll
            for (int n = 0; n < 4; n++)
                acc[m][n] = __builtin_amdgcn_mfma_f32_16x16x32_bf16(af[m], bfv[n], acc[m][n], 0, 0, 0);
        __syncthreads();
    }
    #pragma unroll
    for (int m = 0; m < 4; m++)
        #pragma unroll
        for (int n = 0; n < 4; n++)
            #pragma unroll
            for (int r = 0; r < 4; r++) {
                int o  = row0 + mw + m * 16 + quad * 4 + r;
                int bs = col0 + nw + n * 16 + l15;
                size_t addr = (size_t)(bs >> 10) * ((size_t)NC * HW) + (size_t)o * HW + (bs & 1023);
                out[addr] = acc[m][n][r] + xres[addr];
            }
}

// ---------------------------------------------------------------------------
extern "C" void kernel_launch(void* const* d_in, const int* in_sizes, int n_in,
                              void* d_out, int out_size, void* d_ws, size_t ws_size,
                              hipStream_t stream) {
    const float* x     = (const float*)d_in[0];
    const float* gamma = (const float*)d_in[1];
    const float* beta  = (const float*)d_in[2];
    const float* wqkv  = (const float*)d_in[3];
    const float* wout  = (const float*)d_in[4];
    float* out = (float*)d_out;

    prep_kernel<<<dim3(320), dim3(256), 0, stream>>>(x, gamma, beta, wqkv, wout);
    gemm_qkv<<<dim3(64, 12), dim3(256), 0, stream>>>();
    transpose_v<<<dim3(1024), dim3(256), 0, stream>>>();
    attn_kernel<<<dim3(1024), dim3(256), 0, stream>>>();
    gemm_out<<<dim3(4, 64), dim3(256), 0, stream>>>(x, out);
}